// Round 5
// baseline (699.440 us; speedup 1.0000x reference)
//
#include <hip/hip_runtime.h>
#include <hip/hip_bf16.h>

#define NN  100000   // nodes
#define NE  800000   // edges
#define KIN 384      // input dim
#define HID 256      // hidden dim
#define BN_EPS 1e-5f

typedef __attribute__((ext_vector_type(4))) float floatx4;
typedef __attribute__((ext_vector_type(8))) short short8;

__device__ __forceinline__ unsigned short f2b(float f) {
    union { float f; unsigned int u; } v; v.f = f;
    unsigned int r = v.u + 0x7fffu + ((v.u >> 16) & 1u);   // round-to-nearest-even
    return (unsigned short)(r >> 16);
}
__device__ __forceinline__ float b2f(unsigned short h) {
    union { unsigned int u; float f; } v; v.u = ((unsigned int)h) << 16;
    return v.f;
}

// async 16B global -> LDS (DMA, bypasses VGPRs). LDS side must be
// wave-uniform-base + lane*16 (m104/m108).
__device__ __forceinline__ void gload_lds16(const void* g, void* l) {
    __builtin_amdgcn_global_load_lds(
        (const __attribute__((address_space(1))) void*)g,
        (__attribute__((address_space(3))) void*)l, 16, 0, 0);
}

// ---------------------------------------------------------------------------
// merged: weight transposes (blocks [0, KIN+HID)) + degree count (rest)
__global__ __launch_bounds__(256) void k_prep0(
    const float* __restrict__ W1, unsigned short* __restrict__ W1t,
    const float* __restrict__ W2, unsigned short* __restrict__ W2t,
    const int* __restrict__ dst, int* __restrict__ deg)
{
    const int b = blockIdx.x;
    if (b < KIN) {
        W1t[(size_t)threadIdx.x * KIN + b] = f2b(W1[(size_t)b * HID + threadIdx.x]);
    } else if (b < KIN + HID) {
        const int k2 = b - KIN;
        W2t[(size_t)threadIdx.x * HID + k2] = f2b(W2[(size_t)k2 * HID + threadIdx.x]);
    } else {
        const int i = (b - KIN - HID) * 256 + threadIdx.x;
        if (i < NE) atomicAdd(deg + dst[i], 1);
    }
}

// ---------------------------------------------------------------------------
// hierarchical exclusive scan of deg[NN] -> rowptr[NN+1]; dinv fused in scan1
__device__ __forceinline__ int block_incl_scan(int v, int* lds) {  // 256 threads
    lds[threadIdx.x] = v; __syncthreads();
    #pragma unroll
    for (int off = 1; off < 256; off <<= 1) {
        int t = lds[threadIdx.x];
        int a = (threadIdx.x >= off) ? lds[threadIdx.x - off] : 0;
        __syncthreads();
        lds[threadIdx.x] = t + a;
        __syncthreads();
    }
    return lds[threadIdx.x];
}

__global__ __launch_bounds__(256) void k_scan1(const int* __restrict__ deg,
                                               int* __restrict__ bsum,
                                               float* __restrict__ dinv) {
    __shared__ int lds[256];
    int i = blockIdx.x * 256 + threadIdx.x;
    int v = (i < NN) ? deg[i] : 0;
    if (i < NN) dinv[i] = rsqrtf((float)(v + 1));   // deg + self loop
    int incl = block_incl_scan(v, lds);
    if (threadIdx.x == 255) bsum[blockIdx.x] = incl;
}

__global__ __launch_bounds__(512) void k_scan2(const int* __restrict__ bsum,
                                               int* __restrict__ boff, int nb,
                                               int* __restrict__ rowptr) {
    __shared__ int lds[512];
    int v = (threadIdx.x < nb) ? bsum[threadIdx.x] : 0;
    lds[threadIdx.x] = v; __syncthreads();
    #pragma unroll
    for (int off = 1; off < 512; off <<= 1) {
        int t = lds[threadIdx.x];
        int a = (threadIdx.x >= off) ? lds[threadIdx.x - off] : 0;
        __syncthreads();
        lds[threadIdx.x] = t + a;
        __syncthreads();
    }
    if (threadIdx.x < nb) boff[threadIdx.x] = lds[threadIdx.x] - v;   // exclusive
    if (threadIdx.x == 0) rowptr[NN] = NE;
}

__global__ __launch_bounds__(256) void k_scan3(const int* __restrict__ deg,
                                               const int* __restrict__ boff,
                                               int* __restrict__ rowptr) {
    __shared__ int lds[256];
    int i = blockIdx.x * 256 + threadIdx.x;
    int v = (i < NN) ? deg[i] : 0;
    int incl = block_incl_scan(v, lds);
    if (i < NN) rowptr[i] = incl - v + boff[blockIdx.x];
}

// bucket fill: packed record {src, dinv[src]} per edge, 8B store
__global__ __launch_bounds__(256) void k_fill(
    const int* __restrict__ src, const int* __restrict__ dst,
    const float* __restrict__ dinv, const int* __restrict__ rowptr,
    int* __restrict__ cursor, int2* __restrict__ epk)
{
    int e = blockIdx.x * 256 + threadIdx.x;
    if (e < NE) {
        const int d = dst[e], s = src[e];
        const int pos = rowptr[d] + atomicAdd(cursor + d, 1);
        int2 rec; rec.x = s; rec.y = __float_as_int(dinv[s]);
        epk[pos] = rec;
    }
}

// ---------------------------------------------------------------------------
// bf16 MFMA GEMM, full-width tile: C[M][256](bf16) = A[M][K] * Bt^T
// BM=128, BN=256(=HID), 512 threads / 8 waves of 64x64.
// B staged via async global_load_lds (16B, unpadded LDB=32 — m97 layout).
// A staged through VGPRs (fp32->bf16 or BN+ReLU transform) with register
// prefetch of the next K-tile to hide global latency across the barrier.
template<int K, int MODE, int ABF16>
__global__ __launch_bounds__(512) void k_gemm(
    const void* __restrict__ Av, const unsigned short* __restrict__ Bt,
    unsigned short* __restrict__ C,
    const float* __restrict__ bnacc, const float* __restrict__ g,
    const float* __restrict__ be, int M)
{
    constexpr int BM = 128, BK = 32, LDA = 40, LDB = 32;
    __shared__ __align__(16) unsigned short As[BM * LDA];   // 10.2 KB (padded)
    __shared__ __align__(16) unsigned short Bs[HID * LDB];  // 16 KB (unpadded, DMA)
    __shared__ float s_sc[HID], s_bi[HID];
    const int tid = threadIdx.x;
    const int lane = tid & 63;
    const int wid  = tid >> 6;               // 0..7
    const int wm = wid & 1, wn = wid >> 1;   // 2 x 4 wave grid
    const int l15 = lane & 15, lq = lane >> 4;
    const int row0 = blockIdx.x * BM;

    if (MODE) {
        if (tid < HID) {
            const float inv_n = 1.f / (float)NN;
            const float mu  = bnacc[tid] * inv_n;
            const float var = bnacc[HID + tid] * inv_n - mu * mu;
            const float s   = g[tid] * rsqrtf(var + BN_EPS);
            s_sc[tid] = s;
            s_bi[tid] = be[tid] - s * mu;
        }
        __syncthreads();
    }

    floatx4 acc[4][4] = {};

    const int ar  = tid >> 3;        // 0..63  (fp32 A staging row)
    const int ak  = (tid & 7) * 4;   // 0..28
    const int ar2 = tid >> 2;        // 0..127 (bf16 A staging row)
    const int ak2 = (tid & 3) * 8;   // 0,8,16,24
    // B DMA mapping: wave covers 2 x 1KB segments; lds byte = seg*1024 + lane*16
    const int lofs = (wid << 11) + lane * 16;
    int brow[2], bcol[2];
    #pragma unroll
    for (int r = 0; r < 2; ++r) {
        const int la = lofs + (r << 10);
        brow[r] = la >> 6;           // Bs row (64B rows)
        bcol[r] = (la & 63) >> 1;    // bf16 col within row
    }

    // ---- A prefetch (k0 = 0) ----
    float4 apf0, apf1;
    short8 apf2 = {};
    if (ABF16) {
        const unsigned short* A = (const unsigned short*)Av;
        const int grow = row0 + ar2;
        if (grow < M) apf2 = *(const short8*)(A + (size_t)grow * K + ak2);
    } else {
        const float* A = (const float*)Av;
        const int g0 = row0 + ar, g1 = row0 + 64 + ar;
        apf0 = (g0 < M) ? *(const float4*)(A + (size_t)g0 * K + ak) : make_float4(0.f,0.f,0.f,0.f);
        apf1 = (g1 < M) ? *(const float4*)(A + (size_t)g1 * K + ak) : make_float4(0.f,0.f,0.f,0.f);
    }

    for (int k0 = 0; k0 < K; k0 += BK) {
        // ---- async B stage: 2 x 16B DMA per thread ----
        #pragma unroll
        for (int r = 0; r < 2; ++r)
            gload_lds16(Bt + (size_t)brow[r] * K + k0 + bcol[r],
                        (char*)Bs + lofs + (r << 10));

        // ---- convert prefetched A -> As ----
        if (ABF16) {
            float x[8];
            #pragma unroll
            for (int t = 0; t < 8; ++t) x[t] = b2f((unsigned short)apf2[t]);
            if (MODE) {
                float4 s0 = *(const float4*)(s_sc + k0 + ak2);
                float4 s1 = *(const float4*)(s_sc + k0 + ak2 + 4);
                float4 b0 = *(const float4*)(s_bi + k0 + ak2);
                float4 b1 = *(const float4*)(s_bi + k0 + ak2 + 4);
                x[0] = fmaxf(x[0] * s0.x + b0.x, 0.f);
                x[1] = fmaxf(x[1] * s0.y + b0.y, 0.f);
                x[2] = fmaxf(x[2] * s0.z + b0.z, 0.f);
                x[3] = fmaxf(x[3] * s0.w + b0.w, 0.f);
                x[4] = fmaxf(x[4] * s1.x + b1.x, 0.f);
                x[5] = fmaxf(x[5] * s1.y + b1.y, 0.f);
                x[6] = fmaxf(x[6] * s1.z + b1.z, 0.f);
                x[7] = fmaxf(x[7] * s1.w + b1.w, 0.f);
            }
            short8 o;
            #pragma unroll
            for (int t = 0; t < 8; ++t) o[t] = (short)f2b(x[t]);
            *(short8*)(As + ar2 * LDA + ak2) = o;
        } else {
            ushort4 o0, o1;
            o0.x = f2b(apf0.x); o0.y = f2b(apf0.y); o0.z = f2b(apf0.z); o0.w = f2b(apf0.w);
            o1.x = f2b(apf1.x); o1.y = f2b(apf1.y); o1.z = f2b(apf1.z); o1.w = f2b(apf1.w);
            *(ushort4*)(As + ar * LDA + ak) = o0;
            *(ushort4*)(As + (64 + ar) * LDA + ak) = o1;
        }

        // ---- prefetch next A tile (overlaps barrier + MFMA) ----
        const int kn = k0 + BK;
        if (kn < K) {
            if (ABF16) {
                const unsigned short* A = (const unsigned short*)Av;
                const int grow = row0 + ar2;
                apf2 = {};
                if (grow < M) apf2 = *(const short8*)(A + (size_t)grow * K + kn + ak2);
            } else {
                const float* A = (const float*)Av;
                const int g0 = row0 + ar, g1 = row0 + 64 + ar;
                apf0 = (g0 < M) ? *(const float4*)(A + (size_t)g0 * K + kn + ak) : make_float4(0.f,0.f,0.f,0.f);
                apf1 = (g1 < M) ? *(const float4*)(A + (size_t)g1 * K + kn + ak) : make_float4(0.f,0.f,0.f,0.f);
            }
        }

        __syncthreads();   // drains DMA (vmcnt) + As stores

        short8 af[4], bf[4];
        #pragma unroll
        for (int i = 0; i < 4; ++i)
            af[i] = *(const short8*)(As + (wm * 64 + i * 16 + l15) * LDA + lq * 8);
        #pragma unroll
        for (int j = 0; j < 4; ++j)
            bf[j] = *(const short8*)(Bs + (wn * 64 + j * 16 + l15) * LDB + lq * 8);
        #pragma unroll
        for (int i = 0; i < 4; ++i)
            #pragma unroll
            for (int j = 0; j < 4; ++j)
                acc[i][j] = __builtin_amdgcn_mfma_f32_16x16x32_bf16(af[i], bf[j], acc[i][j], 0, 0, 0);
        __syncthreads();
    }

    // epilogue: C/D layout col=lane&15, row=(lane>>4)*4+reg
    #pragma unroll
    for (int i = 0; i < 4; ++i) {
        #pragma unroll
        for (int r = 0; r < 4; ++r) {
            const int m = row0 + wm * 64 + i * 16 + lq * 4 + r;
            if (m < M) {
                #pragma unroll
                for (int j = 0; j < 4; ++j) {
                    const int c = wn * 64 + j * 16 + l15;
                    C[(size_t)m * HID + c] = f2b(acc[i][j][r]);
                }
            }
        }
    }
}

// ---------------------------------------------------------------------------
// CSR gather: one wave per node; lanes 0-31 even edges, 32-63 odd edges;
// each lane reads ushort8 (16B), 8 rows in flight per wave, loads hoisted
// in explicit batches. Fused BN sum/sumsq stats. Grid oversubscribed.
__global__ __launch_bounds__(256) void k_gather(
    const unsigned short* __restrict__ H, const int2* __restrict__ epk,
    const int* __restrict__ rowptr, const float* __restrict__ dinv,
    unsigned short* __restrict__ AGGb, float* __restrict__ bn_acc)
{
    __shared__ float ls[512];
    const int tid = threadIdx.x, lane = tid & 63, w = tid >> 6;
    const int half = lane >> 5;          // 0 / 1
    const int l32  = lane & 31;
    const int c0   = l32 * 8;            // 8 columns per lane
    float s[8] = {}, q[8] = {};          // BN stats (lanes<32 valid at end)

    for (int n = blockIdx.x * 4 + w; n < NN; n += gridDim.x * 4) {
        const int beg = rowptr[n], end = rowptr[n + 1];
        const float di = dinv[n];
        float a[8] = {};
        int j = beg;
        for (; j + 8 <= end; j += 8) {       // 8 edges / iter, 8 rows in flight
            int2 e[4]; short8 h[4];
            #pragma unroll
            for (int t = 0; t < 4; ++t) e[t] = epk[j + half + 2 * t];
            #pragma unroll
            for (int t = 0; t < 4; ++t)
                h[t] = *(const short8*)(H + (size_t)e[t].x * HID + c0);
            #pragma unroll
            for (int t = 0; t < 4; ++t) {
                const float cf = __int_as_float(e[t].y) * di;
                #pragma unroll
                for (int u = 0; u < 8; ++u)
                    a[u] += b2f((unsigned short)h[t][u]) * cf;
            }
        }
        for (; j + 2 <= end; j += 2) {       // pair tail
            const int2 e = epk[j + half];
            const float cf = __int_as_float(e.y) * di;
            const short8 h = *(const short8*)(H + (size_t)e.x * HID + c0);
            #pragma unroll
            for (int u = 0; u < 8; ++u)
                a[u] += b2f((unsigned short)h[u]) * cf;
        }
        if (j < end && half == 0) {          // odd last edge
            const int2 e = epk[j];
            const float cf = __int_as_float(e.y) * di;
            const short8 h = *(const short8*)(H + (size_t)e.x * HID + c0);
            #pragma unroll
            for (int u = 0; u < 8; ++u)
                a[u] += b2f((unsigned short)h[u]) * cf;
        }
        if (half == 1) {                     // self loop on upper half
            const float cs = di * di;
            const short8 h = *(const short8*)(H + (size_t)n * HID + c0);
            #pragma unroll
            for (int u = 0; u < 8; ++u)
                a[u] += b2f((unsigned short)h[u]) * cs;
        }
        #pragma unroll
        for (int u = 0; u < 8; ++u)
            a[u] += __shfl_xor(a[u], 32);    // fold halves (both get total)
        if (half == 0) {
            short8 o;
            #pragma unroll
            for (int u = 0; u < 8; ++u) o[u] = (short)f2b(a[u]);
            *(short8*)(AGGb + (size_t)n * HID + c0) = o;
            #pragma unroll
            for (int u = 0; u < 8; ++u) { s[u] += a[u]; q[u] += a[u] * a[u]; }
        }
    }

    // block-level BN stat reduction: 4 waves x lanes<32, 8 cols each
    ls[tid] = 0.f; ls[tid + 256] = 0.f;
    __syncthreads();
    if (half == 0) {
        #pragma unroll
        for (int u = 0; u < 8; ++u) {
            atomicAdd(&ls[c0 + u], s[u]);
            atomicAdd(&ls[256 + c0 + u], q[u]);
        }
    }
    __syncthreads();
    atomicAdd(bn_acc + tid, ls[tid]);
    atomicAdd(bn_acc + 256 + tid, ls[tid + 256]);
}

// final BN2 + ReLU: bf16 AGG -> fp32 out; affine computed inline from bn_acc
__global__ __launch_bounds__(256) void k_apply(
    const unsigned short* __restrict__ AGGb, const float* __restrict__ bnacc,
    const float* __restrict__ g, const float* __restrict__ be,
    float* __restrict__ out)
{
    const int gid = blockIdx.x * 256 + threadIdx.x;   // one ushort4 / thread
    if (gid < NN * (HID / 4)) {
        const int c4 = (gid & 63) * 4;
        float sc[4], bi[4];
        const float inv_n = 1.f / (float)NN;
        #pragma unroll
        for (int u = 0; u < 4; ++u) {
            const int c = c4 + u;
            const float mu  = bnacc[c] * inv_n;
            const float var = bnacc[HID + c] * inv_n - mu * mu;
            const float sv  = g[c] * rsqrtf(var + BN_EPS);
            sc[u] = sv; bi[u] = be[c] - sv * mu;
        }
        ushort4 v = *(const ushort4*)(AGGb + (size_t)gid * 4);
        float4 o;
        o.x = fmaxf(b2f(v.x) * sc[0] + bi[0], 0.f);
        o.y = fmaxf(b2f(v.y) * sc[1] + bi[1], 0.f);
        o.z = fmaxf(b2f(v.z) * sc[2] + bi[2], 0.f);
        o.w = fmaxf(b2f(v.w) * sc[3] + bi[3], 0.f);
        *(float4*)(out + (size_t)gid * 4) = o;
    }
}

// ---------------------------------------------------------------------------
extern "C" void kernel_launch(void* const* d_in, const int* in_sizes, int n_in,
                              void* d_out, int out_size, void* d_ws, size_t ws_size,
                              hipStream_t stream)
{
    const float* x   = (const float*)d_in[0];
    const int*   ei  = (const int*)d_in[1];
    const float* W1  = (const float*)d_in[2];
    const float* g1  = (const float*)d_in[4];
    const float* be1 = (const float*)d_in[5];
    const float* W2  = (const float*)d_in[6];
    const float* g2  = (const float*)d_in[8];
    const float* be2 = (const float*)d_in[9];
    float* out = (float*)d_out;
    const int* srcp = ei;
    const int* dstp = ei + NE;

    constexpr int NB = (NN + 255) / 256;   // 391 scan blocks

    char* p = (char*)d_ws;
    // zero-init region (single memset): deg, cursor, bn1, bn2
    int*            deg    = (int*)p;             p += (size_t)NN * 4;
    int*            cursor = (int*)p;             p += (size_t)NN * 4;
    float*          bn1    = (float*)p;           p += 512 * 4;
    float*          bn2    = (float*)p;           p += 512 * 4;
    const size_t zbytes = (size_t)NN * 8 + 4096;
    // rest
    unsigned short* AGGb   = (unsigned short*)p;  p += (size_t)NN * HID * 2;   // 51.2 MB
    unsigned short* H      = (unsigned short*)p;  p += (size_t)NN * HID * 2;   // 51.2 MB
    float*          dinv   = (float*)p;           p += (size_t)NN * 4;
    int*            rowptr = (int*)p;             p += (size_t)(NN + 1) * 4;
    int2*           epk    = (int2*)p;            p += (size_t)NE * 8;         // 6.4 MB
    int*            bsum   = (int*)p;             p += 512 * 4;
    int*            boff   = (int*)p;             p += 512 * 4;
    unsigned short* W1t    = (unsigned short*)p;  p += (size_t)KIN * HID * 2;
    unsigned short* W2t    = (unsigned short*)p;  p += (size_t)HID * HID * 2;

    hipMemsetAsync(deg, 0, zbytes, stream);

    // merged: weight transposes + degree count
    k_prep0<<<KIN + HID + (NE + 255) / 256, 256, 0, stream>>>(W1, W1t, W2, W2t, dstp, deg);

    // graph prep: scan(+dinv) -> fill
    k_scan1<<<NB, 256, 0, stream>>>(deg, bsum, dinv);
    k_scan2<<<1, 512, 0, stream>>>(bsum, boff, NB, rowptr);
    k_scan3<<<NB, 256, 0, stream>>>(deg, boff, rowptr);
    k_fill<<<(NE + 255) / 256, 256, 0, stream>>>(srcp, dstp, dinv, rowptr, cursor, epk);

    const int ggrid = (NN + 127) / 128;   // 782 row-tiles, full 256-col width

    // ---- layer 1 ----
    k_gemm<KIN, 0, 0><<<ggrid, 512, 0, stream>>>(x, W1t, H, nullptr, nullptr, nullptr, NN);
    k_gather<<<2560, 256, 0, stream>>>(H, epk, rowptr, dinv, AGGb, bn1);

    // ---- layer 2 (BN1+ReLU fused into GEMM2 A-stage from raw bn stats) ----
    k_gemm<HID, 1, 1><<<ggrid, 512, 0, stream>>>(AGGb, W2t, H, bn1, g1, be1, NN);
    k_gather<<<2560, 256, 0, stream>>>(H, epk, rowptr, dinv, AGGb, bn2);
    k_apply<<<(NN * (HID / 4) + 255) / 256, 256, 0, stream>>>(AGGb, bn2, g2, be2, out);
}

// Round 6
// 660.374 us; speedup vs baseline: 1.0592x; 1.0592x over previous
//
#include <hip/hip_runtime.h>
#include <hip/hip_bf16.h>

#define NN  100000   // nodes
#define NE  800000   // edges
#define KIN 384      // input dim
#define HID 256      // hidden dim
#define BN_EPS 1e-5f

typedef __attribute__((ext_vector_type(4))) float floatx4;
typedef __attribute__((ext_vector_type(8))) short short8;

__device__ __forceinline__ unsigned short f2b(float f) {
    union { float f; unsigned int u; } v; v.f = f;
    unsigned int r = v.u + 0x7fffu + ((v.u >> 16) & 1u);   // round-to-nearest-even
    return (unsigned short)(r >> 16);
}
__device__ __forceinline__ float b2f(unsigned short h) {
    union { unsigned int u; float f; } v; v.u = ((unsigned int)h) << 16;
    return v.f;
}

// async 16B global -> LDS (DMA). LDS dest = wave-uniform base + lane*16.
__device__ __forceinline__ void gload_lds16(const void* g, void* l) {
    __builtin_amdgcn_global_load_lds(
        (const __attribute__((address_space(1))) void*)g,
        (__attribute__((address_space(3))) void*)l, 16, 0, 0);
}

// ---------------------------------------------------------------------------
// merged: weight transposes (blocks [0, KIN+HID)) + degree count (rest)
__global__ __launch_bounds__(256) void k_prep0(
    const float* __restrict__ W1, unsigned short* __restrict__ W1t,
    const float* __restrict__ W2, unsigned short* __restrict__ W2t,
    const int* __restrict__ dst, int* __restrict__ deg)
{
    const int b = blockIdx.x;
    if (b < KIN) {
        W1t[(size_t)threadIdx.x * KIN + b] = f2b(W1[(size_t)b * HID + threadIdx.x]);
    } else if (b < KIN + HID) {
        const int k2 = b - KIN;
        W2t[(size_t)threadIdx.x * HID + k2] = f2b(W2[(size_t)k2 * HID + threadIdx.x]);
    } else {
        const int i = (b - KIN - HID) * 256 + threadIdx.x;
        if (i < NE) atomicAdd(deg + dst[i], 1);
    }
}

// ---------------------------------------------------------------------------
// scan stage 1: per-block inclusive scan totals + dinv
__device__ __forceinline__ int block_incl_scan(int v, int* lds) {  // 256 threads
    lds[threadIdx.x] = v; __syncthreads();
    #pragma unroll
    for (int off = 1; off < 256; off <<= 1) {
        int t = lds[threadIdx.x];
        int a = (threadIdx.x >= off) ? lds[threadIdx.x - off] : 0;
        __syncthreads();
        lds[threadIdx.x] = t + a;
        __syncthreads();
    }
    return lds[threadIdx.x];
}

__global__ __launch_bounds__(256) void k_scan1(const int* __restrict__ deg,
                                               int* __restrict__ bsum,
                                               float* __restrict__ dinv) {
    __shared__ int lds[256];
    int i = blockIdx.x * 256 + threadIdx.x;
    int v = (i < NN) ? deg[i] : 0;
    if (i < NN) dinv[i] = rsqrtf((float)(v + 1));   // deg + self loop
    int incl = block_incl_scan(v, lds);
    if (threadIdx.x == 255) bsum[blockIdx.x] = incl;
}

// scan stage 2 (merged): each block reduces bsum[0..bid) itself, then does
// its local scan -> rowptr; cursor initialized to rowptr (atomic cursor
// returns final position directly in k_fill).
__global__ __launch_bounds__(256) void k_scan3(const int* __restrict__ deg,
                                               const int* __restrict__ bsum,
                                               int* __restrict__ rowptr,
                                               int* __restrict__ cursor) {
    __shared__ int lds[256];
    const int bid = blockIdx.x;
    int part = 0;
    for (int i = threadIdx.x; i < bid; i += 256) part += bsum[i];
    lds[threadIdx.x] = part; __syncthreads();
    #pragma unroll
    for (int off = 128; off > 0; off >>= 1) {
        if (threadIdx.x < off) lds[threadIdx.x] += lds[threadIdx.x + off];
        __syncthreads();
    }
    const int boff = lds[0];
    __syncthreads();
    const int i = bid * 256 + threadIdx.x;
    const int v = (i < NN) ? deg[i] : 0;
    const int incl = block_incl_scan(v, lds);
    if (i < NN) {
        const int rp = incl - v + boff;
        rowptr[i] = rp;
        cursor[i] = rp;
    }
    if (bid == 0 && threadIdx.x == 0) rowptr[NN] = NE;
}

// bucket fill: 4B record (src index only); cursor pre-seeded with rowptr
__global__ __launch_bounds__(256) void k_fill(
    const int* __restrict__ src, const int* __restrict__ dst,
    int* __restrict__ cursor, int* __restrict__ eidx)
{
    int e = blockIdx.x * 256 + threadIdx.x;
    if (e < NE) {
        const int pos = atomicAdd(cursor + dst[e], 1);
        eidx[pos] = src[e];
    }
}

// ---------------------------------------------------------------------------
// bf16 MFMA GEMM, full-width tile: C[M][256](bf16) = A[M][K] * Bt^T
// BM=128, BN=256(=HID), 512 threads / 8 waves of 64x64.
// B staged via async global_load_lds (16B, unpadded LDB=32 — m97 layout).
// A staged through VGPRs with register prefetch of the next K-tile.
template<int K, int MODE, int ABF16>
__global__ __launch_bounds__(512) void k_gemm(
    const void* __restrict__ Av, const unsigned short* __restrict__ Bt,
    unsigned short* __restrict__ C,
    const float* __restrict__ bnacc, const float* __restrict__ g,
    const float* __restrict__ be, int M)
{
    constexpr int BM = 128, BK = 32, LDA = 40, LDB = 32;
    __shared__ __align__(16) unsigned short As[BM * LDA];   // padded (VGPR stores)
    __shared__ __align__(16) unsigned short Bs[HID * LDB];  // unpadded (DMA)
    __shared__ float s_sc[HID], s_bi[HID];
    const int tid = threadIdx.x;
    const int lane = tid & 63;
    const int wid  = tid >> 6;               // 0..7
    const int wm = wid & 1, wn = wid >> 1;   // 2 x 4 wave grid
    const int l15 = lane & 15, lq = lane >> 4;
    const int row0 = blockIdx.x * BM;

    if (MODE) {
        if (tid < HID) {
            const float inv_n = 1.f / (float)NN;
            const float mu  = bnacc[tid] * inv_n;
            const float var = bnacc[HID + tid] * inv_n - mu * mu;
            const float s   = g[tid] * rsqrtf(var + BN_EPS);
            s_sc[tid] = s;
            s_bi[tid] = be[tid] - s * mu;
        }
        __syncthreads();
    }

    floatx4 acc[4][4] = {};

    const int ar  = tid >> 3;        // 0..63  (fp32 A staging row)
    const int ak  = (tid & 7) * 4;   // 0..28
    const int ar2 = tid >> 2;        // 0..127 (bf16 A staging row)
    const int ak2 = (tid & 3) * 8;   // 0,8,16,24
    // B DMA mapping: wave covers 2 x 1KB segments; lds byte = seg*1024 + lane*16
    const int lofs = (wid << 11) + lane * 16;
    int brow[2], bcol[2];
    #pragma unroll
    for (int r = 0; r < 2; ++r) {
        const int la = lofs + (r << 10);
        brow[r] = la >> 6;           // Bs row (64B rows)
        bcol[r] = (la & 63) >> 1;    // bf16 col within row
    }

    // ---- A prefetch (k0 = 0) ----
    float4 apf0, apf1;
    short8 apf2 = {};
    if (ABF16) {
        const unsigned short* A = (const unsigned short*)Av;
        const int grow = row0 + ar2;
        if (grow < M) apf2 = *(const short8*)(A + (size_t)grow * K + ak2);
    } else {
        const float* A = (const float*)Av;
        const int g0 = row0 + ar, g1 = row0 + 64 + ar;
        apf0 = (g0 < M) ? *(const float4*)(A + (size_t)g0 * K + ak) : make_float4(0.f,0.f,0.f,0.f);
        apf1 = (g1 < M) ? *(const float4*)(A + (size_t)g1 * K + ak) : make_float4(0.f,0.f,0.f,0.f);
    }

    for (int k0 = 0; k0 < K; k0 += BK) {
        // ---- async B stage: 2 x 16B DMA per thread ----
        #pragma unroll
        for (int r = 0; r < 2; ++r)
            gload_lds16(Bt + (size_t)brow[r] * K + k0 + bcol[r],
                        (char*)Bs + lofs + (r << 10));

        // ---- convert prefetched A -> As ----
        if (ABF16) {
            float x[8];
            #pragma unroll
            for (int t = 0; t < 8; ++t) x[t] = b2f((unsigned short)apf2[t]);
            if (MODE) {
                float4 s0 = *(const float4*)(s_sc + k0 + ak2);
                float4 s1 = *(const float4*)(s_sc + k0 + ak2 + 4);
                float4 b0 = *(const float4*)(s_bi + k0 + ak2);
                float4 b1 = *(const float4*)(s_bi + k0 + ak2 + 4);
                x[0] = fmaxf(x[0] * s0.x + b0.x, 0.f);
                x[1] = fmaxf(x[1] * s0.y + b0.y, 0.f);
                x[2] = fmaxf(x[2] * s0.z + b0.z, 0.f);
                x[3] = fmaxf(x[3] * s0.w + b0.w, 0.f);
                x[4] = fmaxf(x[4] * s1.x + b1.x, 0.f);
                x[5] = fmaxf(x[5] * s1.y + b1.y, 0.f);
                x[6] = fmaxf(x[6] * s1.z + b1.z, 0.f);
                x[7] = fmaxf(x[7] * s1.w + b1.w, 0.f);
            }
            short8 o;
            #pragma unroll
            for (int t = 0; t < 8; ++t) o[t] = (short)f2b(x[t]);
            *(short8*)(As + ar2 * LDA + ak2) = o;
        } else {
            ushort4 o0, o1;
            o0.x = f2b(apf0.x); o0.y = f2b(apf0.y); o0.z = f2b(apf0.z); o0.w = f2b(apf0.w);
            o1.x = f2b(apf1.x); o1.y = f2b(apf1.y); o1.z = f2b(apf1.z); o1.w = f2b(apf1.w);
            *(ushort4*)(As + ar * LDA + ak) = o0;
            *(ushort4*)(As + (64 + ar) * LDA + ak) = o1;
        }

        // ---- prefetch next A tile (overlaps barrier + MFMA) ----
        const int kn = k0 + BK;
        if (kn < K) {
            if (ABF16) {
                const unsigned short* A = (const unsigned short*)Av;
                const int grow = row0 + ar2;
                apf2 = {};
                if (grow < M) apf2 = *(const short8*)(A + (size_t)grow * K + kn + ak2);
            } else {
                const float* A = (const float*)Av;
                const int g0 = row0 + ar, g1 = row0 + 64 + ar;
                apf0 = (g0 < M) ? *(const float4*)(A + (size_t)g0 * K + kn + ak) : make_float4(0.f,0.f,0.f,0.f);
                apf1 = (g1 < M) ? *(const float4*)(A + (size_t)g1 * K + kn + ak) : make_float4(0.f,0.f,0.f,0.f);
            }
        }

        __syncthreads();   // drains DMA (vmcnt) + As stores

        short8 af[4], bf[4];
        #pragma unroll
        for (int i = 0; i < 4; ++i)
            af[i] = *(const short8*)(As + (wm * 64 + i * 16 + l15) * LDA + lq * 8);
        #pragma unroll
        for (int j = 0; j < 4; ++j)
            bf[j] = *(const short8*)(Bs + (wn * 64 + j * 16 + l15) * LDB + lq * 8);
        #pragma unroll
        for (int i = 0; i < 4; ++i)
            #pragma unroll
            for (int j = 0; j < 4; ++j)
                acc[i][j] = __builtin_amdgcn_mfma_f32_16x16x32_bf16(af[i], bf[j], acc[i][j], 0, 0, 0);
        __syncthreads();
    }

    // epilogue: C/D layout col=lane&15, row=(lane>>4)*4+reg
    #pragma unroll
    for (int i = 0; i < 4; ++i) {
        #pragma unroll
        for (int r = 0; r < 4; ++r) {
            const int m = row0 + wm * 64 + i * 16 + lq * 4 + r;
            if (m < M) {
                #pragma unroll
                for (int j = 0; j < 4; ++j) {
                    const int c = wn * 64 + j * 16 + l15;
                    C[(size_t)m * HID + c] = f2b(acc[i][j][r]);
                }
            }
        }
    }
}

// ---------------------------------------------------------------------------
// CSR gather (R4 structure): one wave per node; lanes 0-31 even edges,
// 32-63 odd edges; each lane reads ushort8 (16B), 8 rows in flight/wave.
// coef = dinv[src]*dinv[n] re-derived from L2-resident dinv (4B records).
// bounds(256,6) + grid 1536: full co-residency (R4's measured optimum).
__global__ __launch_bounds__(256, 6) void k_gather(
    const unsigned short* __restrict__ H, const int* __restrict__ eidx,
    const int* __restrict__ rowptr, const float* __restrict__ dinv,
    unsigned short* __restrict__ AGGb, float* __restrict__ bn_acc)
{
    __shared__ float ls[512];
    const int tid = threadIdx.x, lane = tid & 63, w = tid >> 6;
    const int half = lane >> 5;          // 0 / 1
    const int l32  = lane & 31;
    const int c0   = l32 * 8;            // 8 columns per lane
    float s[8] = {}, q[8] = {};          // BN stats (lanes<32 valid at end)

    for (int n = blockIdx.x * 4 + w; n < NN; n += gridDim.x * 4) {
        const int beg = rowptr[n], end = rowptr[n + 1];
        const float di = dinv[n];
        float a[8] = {};
        int j = beg;
        for (; j + 8 <= end; j += 8) {       // 8 edges / iter, 8 rows in flight
            #pragma unroll
            for (int t = 0; t < 4; ++t) {
                const int sidx = eidx[j + half + 2 * t];
                const float cf = dinv[sidx] * di;
                const short8 h = *(const short8*)(H + (size_t)sidx * HID + c0);
                #pragma unroll
                for (int u = 0; u < 8; ++u)
                    a[u] += b2f((unsigned short)h[u]) * cf;
            }
        }
        for (; j + 2 <= end; j += 2) {       // pair tail
            const int sidx = eidx[j + half];
            const float cf = dinv[sidx] * di;
            const short8 h = *(const short8*)(H + (size_t)sidx * HID + c0);
            #pragma unroll
            for (int u = 0; u < 8; ++u)
                a[u] += b2f((unsigned short)h[u]) * cf;
        }
        if (j < end && half == 0) {          // odd last edge
            const int sidx = eidx[j];
            const float cf = dinv[sidx] * di;
            const short8 h = *(const short8*)(H + (size_t)sidx * HID + c0);
            #pragma unroll
            for (int u = 0; u < 8; ++u)
                a[u] += b2f((unsigned short)h[u]) * cf;
        }
        if (half == 1) {                     // self loop on upper half
            const float cs = di * di;
            const short8 h = *(const short8*)(H + (size_t)n * HID + c0);
            #pragma unroll
            for (int u = 0; u < 8; ++u)
                a[u] += b2f((unsigned short)h[u]) * cs;
        }
        #pragma unroll
        for (int u = 0; u < 8; ++u)
            a[u] += __shfl_xor(a[u], 32);    // fold halves (both get total)
        if (half == 0) {
            short8 o;
            #pragma unroll
            for (int u = 0; u < 8; ++u) o[u] = (short)f2b(a[u]);
            *(short8*)(AGGb + (size_t)n * HID + c0) = o;
            #pragma unroll
            for (int u = 0; u < 8; ++u) { s[u] += a[u]; q[u] += a[u] * a[u]; }
        }
    }

    // block-level BN stat reduction: 4 waves x lanes<32, 8 cols each
    ls[tid] = 0.f; ls[tid + 256] = 0.f;
    __syncthreads();
    if (half == 0) {
        #pragma unroll
        for (int u = 0; u < 8; ++u) {
            atomicAdd(&ls[c0 + u], s[u]);
            atomicAdd(&ls[256 + c0 + u], q[u]);
        }
    }
    __syncthreads();
    atomicAdd(bn_acc + tid, ls[tid]);
    atomicAdd(bn_acc + 256 + tid, ls[tid + 256]);
}

// final BN2 + ReLU: bf16 AGG -> fp32 out; affine computed inline from bn_acc.
// 16B load / 32B store per thread.
__global__ __launch_bounds__(256) void k_apply(
    const unsigned short* __restrict__ AGGb, const float* __restrict__ bnacc,
    const float* __restrict__ g, const float* __restrict__ be,
    float* __restrict__ out)
{
    const int gid = blockIdx.x * 256 + threadIdx.x;   // one short8 / thread
    if (gid < NN * (HID / 8)) {
        const int c8 = (gid & 31) * 8;
        const float inv_n = 1.f / (float)NN;
        short8 v = *(const short8*)(AGGb + (size_t)gid * 8);
        float o[8];
        #pragma unroll
        for (int u = 0; u < 8; ++u) {
            const int c = c8 + u;
            const float mu  = bnacc[c] * inv_n;
            const float var = bnacc[HID + c] * inv_n - mu * mu;
            const float sv  = g[c] * rsqrtf(var + BN_EPS);
            o[u] = fmaxf(b2f((unsigned short)v[u]) * sv + (be[c] - sv * mu), 0.f);
        }
        float* op = out + (size_t)gid * 8;
        *(float4*)(op)     = make_float4(o[0], o[1], o[2], o[3]);
        *(float4*)(op + 4) = make_float4(o[4], o[5], o[6], o[7]);
    }
}

// ---------------------------------------------------------------------------
extern "C" void kernel_launch(void* const* d_in, const int* in_sizes, int n_in,
                              void* d_out, int out_size, void* d_ws, size_t ws_size,
                              hipStream_t stream)
{
    const float* x   = (const float*)d_in[0];
    const int*   ei  = (const int*)d_in[1];
    const float* W1  = (const float*)d_in[2];
    const float* g1  = (const float*)d_in[4];
    const float* be1 = (const float*)d_in[5];
    const float* W2  = (const float*)d_in[6];
    const float* g2  = (const float*)d_in[8];
    const float* be2 = (const float*)d_in[9];
    float* out = (float*)d_out;
    const int* srcp = ei;
    const int* dstp = ei + NE;

    constexpr int NB = (NN + 255) / 256;   // 391 scan blocks

    char* p = (char*)d_ws;
    // zero-init region (single memset): deg, bn1, bn2
    int*            deg    = (int*)p;             p += (size_t)NN * 4;
    float*          bn1    = (float*)p;           p += 512 * 4;
    float*          bn2    = (float*)p;           p += 512 * 4;
    const size_t zbytes = (size_t)NN * 4 + 4096;
    // rest
    int*            cursor = (int*)p;             p += (size_t)NN * 4;
    unsigned short* AGGb   = (unsigned short*)p;  p += (size_t)NN * HID * 2;   // 51.2 MB
    unsigned short* H      = (unsigned short*)p;  p += (size_t)NN * HID * 2;   // 51.2 MB
    float*          dinv   = (float*)p;           p += (size_t)NN * 4;
    int*            rowptr = (int*)p;             p += (size_t)(NN + 1) * 4;
    int*            eidx   = (int*)p;             p += (size_t)NE * 4;         // 3.2 MB
    int*            bsum   = (int*)p;             p += 512 * 4;
    unsigned short* W1t    = (unsigned short*)p;  p += (size_t)KIN * HID * 2;
    unsigned short* W2t    = (unsigned short*)p;  p += (size_t)HID * HID * 2;

    hipMemsetAsync(deg, 0, zbytes, stream);

    // merged: weight transposes + degree count
    k_prep0<<<KIN + HID + (NE + 255) / 256, 256, 0, stream>>>(W1, W1t, W2, W2t, dstp, deg);

    // graph prep: scan(+dinv) -> scan3(merged offset+rowptr+cursor) -> fill
    k_scan1<<<NB, 256, 0, stream>>>(deg, bsum, dinv);
    k_scan3<<<NB, 256, 0, stream>>>(deg, bsum, rowptr, cursor);
    k_fill<<<(NE + 255) / 256, 256, 0, stream>>>(srcp, dstp, cursor, eidx);

    const int ggrid = (NN + 127) / 128;   // 782 row-tiles, full 256-col width

    // ---- layer 1 ----
    k_gemm<KIN, 0, 0><<<ggrid, 512, 0, stream>>>(x, W1t, H, nullptr, nullptr, nullptr, NN);
    k_gather<<<1536, 256, 0, stream>>>(H, eidx, rowptr, dinv, AGGb, bn1);

    // ---- layer 2 (BN1+ReLU fused into GEMM2 A-stage from raw bn stats) ----
    k_gemm<HID, 1, 1><<<ggrid, 512, 0, stream>>>(AGGb, W2t, H, bn1, g1, be1, NN);
    k_gather<<<1536, 256, 0, stream>>>(H, eidx, rowptr, dinv, AGGb, bn2);
    k_apply<<<(NN * (HID / 8) + 255) / 256, 256, 0, stream>>>(AGGb, bn2, g2, be2, out);
}